// Round 8
// baseline (248.556 us; speedup 1.0000x reference)
//
#include <hip/hip_runtime.h>
#include <hip/hip_fp16.h>

// DAS beamforming: out[b,z,x,k] = sum_c lerp(rf[b,c], delay(b,c,z,x))[k]
// Round 13: R10's fp16 double-buffer at FOUR blocks/CU.
//  Post-mortem chain: das is ~39-43 us across {f32,fp16} x {16,8,1 barriers}
//  x {2,16}-deep staging MLP -> every throughput model falsified (VALU ~7,
//  LDS gather floor ~6-12, L2 staging ~8, HBM ~10 us). VALUBusy ~13% at
//  ~80% occupancy says resident-but-WAITING: latency-exposure-bound.
//  All rounds since R9 ran ONE block/CU, so phase drains + sqrt->ds_read
//  dep chains expose latency with no independent work. R5 (2 blocks/CU) was
//  the best healthy config; R11's 2-block failure was chunk-thrash +
//  allocating partials (since fixed by NT stores), not co-residency.
//  fp16's 32 KB/block double buffer -> 4 blocks/CU in 128 KB LDS:
//  THREADS=512, PX=4, C_PER_BLOCK=8, 16 chunks, grid 1024, 32 waves/CU,
//  launch_bounds(512,8) caps VGPR at 64. One block's barrier drain is
//  covered by three other blocks' compute.
//  Kept: reg-staged fp16 cvt from CLEAN rf (never read ws), T14 async split,
//  chunk=bid&15 XCD pinning (rf 1 MB/L2), NT partials + 16-chunk reduce.

#define NBATCH 2
#define NC 128
#define NS 2048
#define NK 4
#define NM 65536                              // Nz*Nx pixels per batch

#define THREADS 512
#define PX_PER_THREAD 4
#define PX_PER_BLOCK (THREADS * PX_PER_THREAD)   // 2048
#define C_PER_BLOCK 8
#define N_CHUNKS (NC / C_PER_BLOCK)           // 16
#define N_TILES (NM / PX_PER_BLOCK)           // 32
#define NBLOCKS (NBATCH * N_TILES * N_CHUNKS) // 1024 = 4 blocks/CU

#define PART_BYTES ((size_t)N_CHUNKS * NBATCH * NM * NK * 4)  // 33.6 MB

typedef float f32x4 __attribute__((ext_vector_type(4)));

// pack 8 f32 -> 8 f16 (one half4 sample pair) for LDS residency
__device__ __forceinline__ uint4 cvt8(float4 a, float4 b) {
    const __half2 h0 = __floats2half2_rn(a.x, a.y);
    const __half2 h1 = __floats2half2_rn(a.z, a.w);
    const __half2 h2 = __floats2half2_rn(b.x, b.y);
    const __half2 h3 = __floats2half2_rn(b.z, b.w);
    return make_uint4(__builtin_bit_cast(unsigned, h0),
                      __builtin_bit_cast(unsigned, h1),
                      __builtin_bit_cast(unsigned, h2),
                      __builtin_bit_cast(unsigned, h3));
}

template <bool ATOMIC>
__global__ __launch_bounds__(THREADS, 8) void das_kernel(
    const float* __restrict__ rf, const float* __restrict__ g,
    const float* __restrict__ pr, const float* __restrict__ p,
    float* __restrict__ dst)    // ATOMIC ? out : partials in ws
{
    __shared__ uint4 sbuf[2][NS / 2];   // 2 x 16 KiB fp16 double buffer

    const int bid   = blockIdx.x;
    const int chunk = bid & (N_CHUNKS - 1);          // chunk&7 == XCD id
    const int tile  = (bid >> 4) & (N_TILES - 1);
    const int b     = bid >> 9;
    const int t     = threadIdx.x;
    const int px0   = tile * PX_PER_BLOCK;

    const float c0v = p[b * 4 + 0];
    const float fsv = p[b * 4 + 1];
    const float t0v = p[b * 4 + 2];
    const float scale = fsv / c0v;            // samples per meter
    const float sb0   = scale * t0v;

    float gx[PX_PER_THREAD], gy[PX_PER_THREAD], gzv[PX_PER_THREAD];
#pragma unroll
    for (int j = 0; j < PX_PER_THREAD; ++j) {
        const int m = px0 + j * THREADS + t;
        const float* gp = g + ((size_t)b * NM + m) * 3;
        gx[j]  = gp[0];
        gy[j]  = gp[1];
        gzv[j] = gp[2];
    }

    float4 acc[PX_PER_THREAD];
#pragma unroll
    for (int j = 0; j < PX_PER_THREAD; ++j) acc[j] = make_float4(0.f, 0.f, 0.f, 0.f);

    const int ch0 = chunk * C_PER_BLOCK;
    const float* slice0 = rf + (size_t)(b * NC + ch0) * NS * NK;

    // initial stage: slice 0 -> regs -> fp16 -> buf0. 512 threads x 4 float4:
    // thread t owns uint4 slots t and t+512 (each a wave-contiguous 16 B).
    {
        const float4* s4 = (const float4*)slice0;
        const float4 a0 = s4[2 * t];
        const float4 a1 = s4[2 * t + 1];
        const float4 b0 = s4[2 * (t + THREADS)];
        const float4 b1 = s4[2 * (t + THREADS) + 1];
        sbuf[0][t]           = cvt8(a0, a1);
        sbuf[0][t + THREADS] = cvt8(b0, b1);
    }

    for (int cc = 0; cc < C_PER_BLOCK; ++cc) {
        // barrier publishes buf (cc&1) writes from the previous iteration and
        // guarantees everyone finished reading buf ((cc+1)&1) two iters ago.
        __syncthreads();

        // T14 async split: issue next slice's global loads NOW; the vmcnt
        // drain + cvt + ds_write happen after this iteration's compute.
        float4 a0, a1, b0, b1;
        if (cc + 1 < C_PER_BLOCK) {
            const float4* s4 = (const float4*)(slice0 + (size_t)(cc + 1) * NS * NK);
            a0 = s4[2 * t];
            a1 = s4[2 * t + 1];
            b0 = s4[2 * (t + THREADS)];
            b1 = s4[2 * (t + THREADS) + 1];
        }

        const uint2* lb = (const uint2*)&sbuf[cc & 1][0];   // half4 samples
        const float* prp = pr + ((size_t)(b * NC + ch0 + cc)) * 3;
        const float prx = prp[0], pry = prp[1], prz = prp[2];

#pragma unroll
        for (int j = 0; j < PX_PER_THREAD; ++j) {
            const float dx = gx[j]  - prx;
            const float dy = gy[j]  - pry;
            const float dz = gzv[j] - prz;
            const float drx = __builtin_amdgcn_sqrtf(fmaf(dx, dx, fmaf(dy, dy, dz * dz)));
            float s = fmaf(scale, gzv[j] + drx, sb0);      // fs*(t0+gz+drx)/c0
            s = fminf(fmaxf(s, 0.0f), (float)(NS - 1));    // clamp
            const float fi = fminf(floorf(s), (float)(NS - 2));
            const float w  = s - fi;
            const float wm = 1.0f - w;
            const int i0 = (int)fi;
            const uint2 u0 = lb[i0];          // half4 y0 | contiguous 16 B:
            const uint2 u1 = lb[i0 + 1];      // half4 y1 | one ds_read2_b64
            const float2 y0a = __half22float2(__builtin_bit_cast(__half2, u0.x));
            const float2 y0b = __half22float2(__builtin_bit_cast(__half2, u0.y));
            const float2 y1a = __half22float2(__builtin_bit_cast(__half2, u1.x));
            const float2 y1b = __half22float2(__builtin_bit_cast(__half2, u1.y));
            acc[j].x = fmaf(y0a.x, wm, fmaf(y1a.x, w, acc[j].x));
            acc[j].y = fmaf(y0a.y, wm, fmaf(y1a.y, w, acc[j].y));
            acc[j].z = fmaf(y0b.x, wm, fmaf(y1b.x, w, acc[j].z));
            acc[j].w = fmaf(y0b.y, wm, fmaf(y1b.y, w, acc[j].w));
        }

        // drain the prefetch (s_waitcnt auto-inserted), convert, publish on
        // the NEXT barrier. Writing buf ((cc+1)&1) is safe: all waves passed
        // the barrier above, so nobody still reads it from iteration cc-1.
        if (cc + 1 < C_PER_BLOCK) {
            sbuf[(cc + 1) & 1][t]           = cvt8(a0, a1);
            sbuf[(cc + 1) & 1][t + THREADS] = cvt8(b0, b1);
        }
    }

    if (ATOMIC) {
        float* ob = dst + (size_t)b * NM * NK;
#pragma unroll
        for (int j = 0; j < PX_PER_THREAD; ++j) {
            const int m = px0 + j * THREADS + t;
            float* op = ob + (size_t)m * NK;
            atomicAdd(op + 0, acc[j].x);
            atomicAdd(op + 1, acc[j].y);
            atomicAdd(op + 2, acc[j].z);
            atomicAdd(op + 3, acc[j].w);
        }
    } else {
        // partial[chunk][b][m] — disjoint per block. NON-TEMPORAL: write-once
        // data must not allocate in L2/LLC (evicts rf + dirty poison lines).
        f32x4* pw = (f32x4*)dst + (size_t)(chunk * NBATCH + b) * NM;
#pragma unroll
        for (int j = 0; j < PX_PER_THREAD; ++j) {
            const int m = px0 + j * THREADS + t;
            const f32x4 v = {acc[j].x, acc[j].y, acc[j].z, acc[j].w};
            __builtin_nontemporal_store(v, pw + m);
        }
    }
}

// out[i] = sum over 16 chunk partials; i indexes float4 over [B*NM)
__global__ __launch_bounds__(256) void reduce_kernel(
    const f32x4* __restrict__ part, f32x4* __restrict__ out)
{
    const int i = blockIdx.x * 256 + threadIdx.x;
    const size_t stride = (size_t)NBATCH * NM;
    f32x4 a = __builtin_nontemporal_load(part + i);
#pragma unroll
    for (int c = 1; c < N_CHUNKS; ++c) {
        const f32x4 v = __builtin_nontemporal_load(part + c * stride + i);
        a += v;
    }
    out[i] = a;
}

extern "C" void kernel_launch(void* const* d_in, const int* in_sizes, int n_in,
                              void* d_out, int out_size, void* d_ws, size_t ws_size,
                              hipStream_t stream) {
    (void)in_sizes; (void)n_in;
    const float* rf = (const float*)d_in[0];
    const float* g  = (const float*)d_in[1];
    const float* pr = (const float*)d_in[2];
    const float* p  = (const float*)d_in[3];
    float* out = (float*)d_out;

    if (ws_size >= PART_BYTES) {
        das_kernel<false><<<NBLOCKS, THREADS, 0, stream>>>(rf, g, pr, p, (float*)d_ws);
        reduce_kernel<<<(NBATCH * NM) / 256, 256, 0, stream>>>((const f32x4*)d_ws,
                                                               (f32x4*)out);
    } else {
        (void)hipMemsetAsync(d_out, 0, (size_t)out_size * sizeof(float), stream);
        das_kernel<true><<<NBLOCKS, THREADS, 0, stream>>>(rf, g, pr, p, out);
    }
}

// Round 9
// 91.780 us; speedup vs baseline: 2.7082x; 2.7082x over previous
//
#include <hip/hip_runtime.h>
#include <hip/hip_fp16.h>

// DAS beamforming: out[b,z,x,k] = sum_c lerp(rf[b,c], delay(b,c,z,x))[k]
// Round 14: minimum-allocation-footprint das (R10 skeleton, 4 chunks).
//  Post-mortem R11/R13: health = per-XCD working set (rf + partial stream)
//  must fit 4 MB L2. 16-chunk partials (4.2 MB/XCD) + multi-block/CU thrash
//  rf -> 203 MB HBM fetch + 2x poison-writeback amplification -> das 189 us.
//  NT stores do NOT prevent allocation pressure (R13 proof). Healthy configs
//  (<=2.1 MB/XCD partials, 1 block/CU) all sit at das ~40 us regardless of
//  barriers/MLP/fp16 -> intra-block structure exhausted; remaining lever is
//  das's own cache-allocation footprint (each allocated MB costs ~2 MB HBM
//  against the poison-dirty LLC) and epilogue volume.
//  This round: 4 chunks. C_PER_BLOCK=32, PX=2, grid 256 = 1 block/CU.
//  Partials 8.4 MB (1 MB/XCD stream); chunk=bid&3 + XCD=bid%8 -> each XCD
//  serves ONE chunk: rf footprint 2 MB/XCD. Staging 268 MB L2-served (R5
//  proved fine). 4-way reduce. sbase hoist restored (-1 VALU/pair).
//  Kept: reg-staged fp16 cvt from CLEAN rf (never read ws), T14 async split,
//  fp16 double-buffer (2x16 KB), NT f32 partials, reduce kernel.

#define NBATCH 2
#define NC 128
#define NS 2048
#define NK 4
#define NM 65536                              // Nz*Nx pixels per batch

#define THREADS 1024
#define PX_PER_THREAD 2
#define PX_PER_BLOCK (THREADS * PX_PER_THREAD)   // 2048
#define C_PER_BLOCK 32
#define N_CHUNKS (NC / C_PER_BLOCK)           // 4
#define N_TILES (NM / PX_PER_BLOCK)           // 32
#define NBLOCKS (NBATCH * N_TILES * N_CHUNKS) // 256 = 1 block/CU

#define PART_BYTES ((size_t)N_CHUNKS * NBATCH * NM * NK * 4)  // 8.4 MB

typedef float f32x4 __attribute__((ext_vector_type(4)));

// pack 8 f32 -> 8 f16 (one half4 sample pair) for LDS residency
__device__ __forceinline__ uint4 cvt8(float4 a, float4 b) {
    const __half2 h0 = __floats2half2_rn(a.x, a.y);
    const __half2 h1 = __floats2half2_rn(a.z, a.w);
    const __half2 h2 = __floats2half2_rn(b.x, b.y);
    const __half2 h3 = __floats2half2_rn(b.z, b.w);
    return make_uint4(__builtin_bit_cast(unsigned, h0),
                      __builtin_bit_cast(unsigned, h1),
                      __builtin_bit_cast(unsigned, h2),
                      __builtin_bit_cast(unsigned, h3));
}

template <bool ATOMIC>
__global__ __launch_bounds__(THREADS, 4) void das_kernel(
    const float* __restrict__ rf, const float* __restrict__ g,
    const float* __restrict__ pr, const float* __restrict__ p,
    float* __restrict__ dst)    // ATOMIC ? out : partials in ws
{
    __shared__ uint4 sbuf[2][NS / 2];   // 2 x 16 KiB fp16 double buffer

    const int bid   = blockIdx.x;
    const int chunk = bid & (N_CHUNKS - 1);       // chunk = XCD%4: one chunk
    const int tile  = (bid >> 2) & (N_TILES - 1); // per XCD -> rf 2 MB/L2
    const int b     = bid >> 7;
    const int t     = threadIdx.x;
    const int px0   = tile * PX_PER_BLOCK;

    const float c0v = p[b * 4 + 0];
    const float fsv = p[b * 4 + 1];
    const float t0v = p[b * 4 + 2];
    const float scale = fsv / c0v;            // samples per meter
    const float sb0   = scale * t0v;

    float gx[PX_PER_THREAD], gy[PX_PER_THREAD], gzv[PX_PER_THREAD],
          sbase[PX_PER_THREAD];
#pragma unroll
    for (int j = 0; j < PX_PER_THREAD; ++j) {
        const int m = px0 + j * THREADS + t;
        const float* gp = g + ((size_t)b * NM + m) * 3;
        gx[j]  = gp[0];
        gy[j]  = gp[1];
        gzv[j] = gp[2];
        sbase[j] = fmaf(scale, gzv[j], sb0);  // fs*(t0 + d_tx)/c0 hoisted
    }

    float4 acc[PX_PER_THREAD];
#pragma unroll
    for (int j = 0; j < PX_PER_THREAD; ++j) acc[j] = make_float4(0.f, 0.f, 0.f, 0.f);

    const int ch0 = chunk * C_PER_BLOCK;
    const float* slice0 = rf + (size_t)(b * NC + ch0) * NS * NK;

    // initial stage: slice 0 -> regs -> fp16 -> buf0 (thread t owns slot t)
    {
        const float4* s4 = (const float4*)slice0;
        const float4 a0 = s4[2 * t];
        const float4 a1 = s4[2 * t + 1];
        sbuf[0][t] = cvt8(a0, a1);
    }

    for (int cc = 0; cc < C_PER_BLOCK; ++cc) {
        // barrier publishes buf (cc&1) writes from the previous iteration and
        // guarantees everyone finished reading buf ((cc+1)&1) two iters ago.
        __syncthreads();

        // T14 async split: issue next slice's global loads NOW; the vmcnt
        // drain + cvt + ds_write happen after this iteration's compute.
        float4 a0, a1;
        if (cc + 1 < C_PER_BLOCK) {
            const float4* s4 = (const float4*)(slice0 + (size_t)(cc + 1) * NS * NK);
            a0 = s4[2 * t];
            a1 = s4[2 * t + 1];
        }

        const uint2* lb = (const uint2*)&sbuf[cc & 1][0];   // half4 samples
        const float* prp = pr + ((size_t)(b * NC + ch0 + cc)) * 3;
        const float prx = prp[0], pry = prp[1], prz = prp[2];

#pragma unroll
        for (int j = 0; j < PX_PER_THREAD; ++j) {
            const float dx = gx[j]  - prx;
            const float dy = gy[j]  - pry;
            const float dz = gzv[j] - prz;
            const float drx = __builtin_amdgcn_sqrtf(fmaf(dx, dx, fmaf(dy, dy, dz * dz)));
            float s = fmaf(scale, drx, sbase[j]);          // fractional sample
            s = fminf(fmaxf(s, 0.0f), (float)(NS - 1));    // clamp
            const float fi = fminf(floorf(s), (float)(NS - 2));
            const float w  = s - fi;
            const float wm = 1.0f - w;
            const int i0 = (int)fi;
            const uint2 u0 = lb[i0];          // half4 y0 | contiguous 16 B:
            const uint2 u1 = lb[i0 + 1];      // half4 y1 | one ds_read2_b64
            const float2 y0a = __half22float2(__builtin_bit_cast(__half2, u0.x));
            const float2 y0b = __half22float2(__builtin_bit_cast(__half2, u0.y));
            const float2 y1a = __half22float2(__builtin_bit_cast(__half2, u1.x));
            const float2 y1b = __half22float2(__builtin_bit_cast(__half2, u1.y));
            acc[j].x = fmaf(y0a.x, wm, fmaf(y1a.x, w, acc[j].x));
            acc[j].y = fmaf(y0a.y, wm, fmaf(y1a.y, w, acc[j].y));
            acc[j].z = fmaf(y0b.x, wm, fmaf(y1b.x, w, acc[j].z));
            acc[j].w = fmaf(y0b.y, wm, fmaf(y1b.y, w, acc[j].w));
        }

        // drain the prefetch (s_waitcnt auto-inserted), convert, publish on
        // the NEXT barrier. Writing buf ((cc+1)&1) is safe: all waves passed
        // the barrier above, so nobody still reads it from iteration cc-1.
        if (cc + 1 < C_PER_BLOCK)
            sbuf[(cc + 1) & 1][t] = cvt8(a0, a1);
    }

    if (ATOMIC) {
        float* ob = dst + (size_t)b * NM * NK;
#pragma unroll
        for (int j = 0; j < PX_PER_THREAD; ++j) {
            const int m = px0 + j * THREADS + t;
            float* op = ob + (size_t)m * NK;
            atomicAdd(op + 0, acc[j].x);
            atomicAdd(op + 1, acc[j].y);
            atomicAdd(op + 2, acc[j].z);
            atomicAdd(op + 3, acc[j].w);
        }
    } else {
        // partial[chunk][b][m] — disjoint per block, NT float4 stores.
        f32x4* pw = (f32x4*)dst + (size_t)(chunk * NBATCH + b) * NM;
#pragma unroll
        for (int j = 0; j < PX_PER_THREAD; ++j) {
            const int m = px0 + j * THREADS + t;
            const f32x4 v = {acc[j].x, acc[j].y, acc[j].z, acc[j].w};
            __builtin_nontemporal_store(v, pw + m);
        }
    }
}

// out[i] = sum over 4 chunk partials; i indexes float4 over [B*NM)
__global__ __launch_bounds__(256) void reduce_kernel(
    const f32x4* __restrict__ part, f32x4* __restrict__ out)
{
    const int i = blockIdx.x * 256 + threadIdx.x;
    const size_t stride = (size_t)NBATCH * NM;
    f32x4 a = __builtin_nontemporal_load(part + i);
#pragma unroll
    for (int c = 1; c < N_CHUNKS; ++c) {
        const f32x4 v = __builtin_nontemporal_load(part + c * stride + i);
        a += v;
    }
    out[i] = a;
}

extern "C" void kernel_launch(void* const* d_in, const int* in_sizes, int n_in,
                              void* d_out, int out_size, void* d_ws, size_t ws_size,
                              hipStream_t stream) {
    (void)in_sizes; (void)n_in;
    const float* rf = (const float*)d_in[0];
    const float* g  = (const float*)d_in[1];
    const float* pr = (const float*)d_in[2];
    const float* p  = (const float*)d_in[3];
    float* out = (float*)d_out;

    if (ws_size >= PART_BYTES) {
        das_kernel<false><<<NBLOCKS, THREADS, 0, stream>>>(rf, g, pr, p, (float*)d_ws);
        reduce_kernel<<<(NBATCH * NM) / 256, 256, 0, stream>>>((const f32x4*)d_ws,
                                                               (f32x4*)out);
    } else {
        (void)hipMemsetAsync(d_out, 0, (size_t)out_size * sizeof(float), stream);
        das_kernel<true><<<NBLOCKS, THREADS, 0, stream>>>(rf, g, pr, p, out);
    }
}